// Round 1
// baseline (189.282 us; speedup 1.0000x reference)
//
#include <hip/hip_runtime.h>
#include <math.h>

#define BB 32
#define HH 32
#define KHH 8
#define DD 128
#define LL 4096
#define GG 4
#define SCALE 0.08838834764831845f

#define NTHREADS 512
#define NW 8                       // waves per block
#define ROWS_PER_WAVE (LL / NW)    // 512
#define NIT (ROWS_PER_WAVE / 4)    // 128 iterations, 4 rows per wave-iter

__global__ __launch_bounds__(NTHREADS)
void attn_decode(const float* __restrict__ q,
                 const float* __restrict__ knew,
                 const float* __restrict__ vnew,
                 const float* __restrict__ kc,
                 const float* __restrict__ vc,
                 const int* __restrict__ kvi,
                 float* __restrict__ out) {
  __shared__ int   lds_val[LL];          // 16 KB: encoded row source per l
  __shared__ float o_lds[NW][GG][DD];    // 16 KB: per-wave partial O
  __shared__ float m_lds[NW][GG];
  __shared__ float s_lds[NW][GG];
  __shared__ int   lds_loc[BB];

  const int tid  = threadIdx.x;
  const int b    = blockIdx.x >> 3;
  const int kh   = blockIdx.x & 7;
  const int w    = tid >> 6;
  const int lane = tid & 63;
  const int qid  = lane >> 4;   // quarter-wave id 0..3 (one row each per iter)
  const int i16  = lane & 15;   // lane within quarter: dims [8*i16, 8*i16+8)

  // ---- precompute row-source table: val>=0 -> cache row, val<0 -> new-kv batch -(val+1)
  if (tid < BB) lds_loc[tid] = kvi[tid * LL + (LL - 1)];
  __syncthreads();
  for (int l = tid; l < LL; l += NTHREADS) {
    int idx = kvi[b * LL + l];
    int val = idx;
#pragma unroll
    for (int j = 0; j < BB; ++j)
      if (lds_loc[j] == idx) val = -(j + 1);
    lds_val[l] = val;
  }
  __syncthreads();

  // ---- q fragments: 4 heads x 8 dims per lane
  const int khq = kh * GG;
  float qf[GG][8];
#pragma unroll
  for (int g = 0; g < GG; ++g) {
    const float* qp = q + ((size_t)b * HH + (khq + g)) * DD + i16 * 8;
#pragma unroll
    for (int j = 0; j < 8; ++j) qf[g][j] = qp[j];
  }

  float m[GG], s[GG], o[GG][8];
#pragma unroll
  for (int g = 0; g < GG; ++g) {
    m[g] = -INFINITY; s[g] = 0.f;
#pragma unroll
    for (int j = 0; j < 8; ++j) o[g][j] = 0.f;
  }

  const int    base  = w * ROWS_PER_WAVE;
  const size_t khoff = (size_t)kh * DD + i16 * 8;

  auto addr = [&](int it, const float*& kp, const float*& vp) {
    int l   = base + it * 4 + qid;
    int val = lds_val[l];
    int row = (val < 0) ? (-val - 1) : val;
    const float* kb = (val < 0) ? knew : kc;
    const float* vb = (val < 0) ? vnew : vc;
    size_t off = ((size_t)row * (KHH * DD)) + khoff;
    kp = kb + off;
    vp = vb + off;
  };

  // prologue load
  const float *kp, *vp;
  addr(0, kp, vp);
  float4 ka  = *(const float4*)kp;
  float4 kb4 = *(const float4*)(kp + 4);
  float4 va  = *(const float4*)vp;
  float4 vb4 = *(const float4*)(vp + 4);

  for (int it = 0; it < NIT; ++it) {
    float4 nka, nkb, nva, nvb;
    if (it + 1 < NIT) {            // 1-deep prefetch of next rows
      const float *nkp, *nvp;
      addr(it + 1, nkp, nvp);
      nka = *(const float4*)nkp;
      nkb = *(const float4*)(nkp + 4);
      nva = *(const float4*)nvp;
      nvb = *(const float4*)(nvp + 4);
    } else {
      nka = ka; nkb = kb4; nva = va; nvb = vb4;
    }

#pragma unroll
    for (int g = 0; g < GG; ++g) {
      float sc = qf[g][0]*ka.x  + qf[g][1]*ka.y  + qf[g][2]*ka.z  + qf[g][3]*ka.w
               + qf[g][4]*kb4.x + qf[g][5]*kb4.y + qf[g][6]*kb4.z + qf[g][7]*kb4.w;
#pragma unroll
      for (int msk = 1; msk < 16; msk <<= 1)
        sc += __shfl_xor(sc, msk);       // reduce across the 16-lane quarter
      sc *= SCALE;

      if (sc > m[g]) {                   // rare after warm-up; uniform per quarter
        float so = __expf(m[g] - sc);
        m[g] = sc;
        s[g] *= so;
#pragma unroll
        for (int j = 0; j < 8; ++j) o[g][j] *= so;
      }
      float p = __expf(sc - m[g]);
      s[g] += p;
      o[g][0] += p * va.x;  o[g][1] += p * va.y;  o[g][2] += p * va.z;  o[g][3] += p * va.w;
      o[g][4] += p * vb4.x; o[g][5] += p * vb4.y; o[g][6] += p * vb4.z; o[g][7] += p * vb4.w;
    }

    ka = nka; kb4 = nkb; va = nva; vb4 = nvb;
  }

  // ---- merge the 4 quarters within each wave (each quarter covers full D)
#pragma unroll
  for (int g = 0; g < GG; ++g) {
#pragma unroll
    for (int off = 16; off < 64; off <<= 1) {
      float m2 = __shfl_xor(m[g], off);
      float s2 = __shfl_xor(s[g], off);
      float M  = fmaxf(m[g], m2);
      float w1 = __expf(m[g] - M);
      float w2 = __expf(m2 - M);
      s[g] = w1 * s[g] + w2 * s2;
#pragma unroll
      for (int j = 0; j < 8; ++j) {
        float o2 = __shfl_xor(o[g][j], off);
        o[g][j] = w1 * o[g][j] + w2 * o2;
      }
      m[g] = M;
    }
  }

  // ---- per-wave partials to LDS
  if (lane < 16) {
#pragma unroll
    for (int g = 0; g < GG; ++g) {
#pragma unroll
      for (int j = 0; j < 8; ++j) o_lds[w][g][i16 * 8 + j] = o[g][j];
      if (lane == 0) { m_lds[w][g] = m[g]; s_lds[w][g] = s[g]; }
    }
  }
  __syncthreads();

  // ---- cross-wave combine + write: 512 threads -> (g, d)
  {
    int g = tid >> 7;
    int d = tid & 127;
    float M = -INFINITY;
#pragma unroll
    for (int wv = 0; wv < NW; ++wv) M = fmaxf(M, m_lds[wv][g]);
    float ss = 0.f, oo = 0.f;
#pragma unroll
    for (int wv = 0; wv < NW; ++wv) {
      float wt = __expf(m_lds[wv][g] - M);
      ss += wt * s_lds[wv][g];
      oo += wt * o_lds[wv][g][d];
    }
    out[((size_t)b * HH + (khq + g)) * DD + d] = oo / ss;
  }
}

extern "C" void kernel_launch(void* const* d_in, const int* in_sizes, int n_in,
                              void* d_out, int out_size, void* d_ws, size_t ws_size,
                              hipStream_t stream) {
  const float* q    = (const float*)d_in[0];
  const float* knew = (const float*)d_in[1];
  const float* vnew = (const float*)d_in[2];
  const float* kc   = (const float*)d_in[3];
  const float* vc   = (const float*)d_in[4];
  const int*   kvi  = (const int*)d_in[5];
  float* out = (float*)d_out;

  attn_decode<<<dim3(BB * KHH), dim3(NTHREADS), 0, stream>>>(q, knew, vnew, kc, vc, kvi, out);
}